// Round 1
// baseline (681.060 us; speedup 1.0000x reference)
//
#include <hip/hip_runtime.h>
#include <math.h>

#define NRAYS 4096
#define NSAMP 128
#define NPTS (NRAYS * NSAMP)
#define TBL_MASK 0x7FFFFu
#define LVL_STRIDE (524288 * 2)

struct ResArr { float r[16]; };

__device__ __forceinline__ float sigmoidf_(float x) { return 1.f / (1.f + expf(-x)); }

// out[o] = sum_i in[i] * W[i*OUT+o]; optional relu. Fully unrolled so every
// array index is compile-time (register-resident); weight addresses are
// wave-uniform -> scalar loads.
template<int IN, int OUT>
__device__ __forceinline__ void layer(const float (&in)[IN], float (&out)[OUT],
                                      const float* __restrict__ W, bool dorelu)
{
  constexpr int CH = (OUT < 32) ? OUT : 32;  // chunk outputs to cap VGPR peak
  #pragma unroll
  for (int oc = 0; oc < OUT; oc += CH) {
    float acc[CH];
    #pragma unroll
    for (int o = 0; o < CH; ++o) acc[o] = 0.f;
    #pragma unroll
    for (int i = 0; i < IN; ++i) {
      const float x = in[i];
      const float* wr = W + i * OUT + oc;
      #pragma unroll
      for (int o = 0; o < CH; ++o) acc[o] = fmaf(x, wr[o], acc[o]);
    }
    #pragma unroll
    for (int o = 0; o < CH; ++o) out[oc + o] = dorelu ? fmaxf(acc[o], 0.f) : acc[o];
  }
}

__global__ void __launch_bounds__(256)
point_kernel(const float* __restrict__ rays,
             const float* __restrict__ tables,
             const float* __restrict__ ws0, const float* __restrict__ ws1,
             const float* __restrict__ ws2, const float* __restrict__ wc0,
             const float* __restrict__ wc1, const float* __restrict__ wc2,
             const float* __restrict__ wc3, const float* __restrict__ app_table,
             float* __restrict__ raw_out, ResArr RES)
{
  const int p = blockIdx.x * 256 + threadIdx.x;
  const int r = p >> 7;
  const int s = p & (NSAMP - 1);

  const float ox = rays[r * 7 + 0], oy = rays[r * 7 + 1], oz = rays[r * 7 + 2];
  const float dx = rays[r * 7 + 3], dy = rays[r * 7 + 4], dz = rays[r * 7 + 5];
  const int code = (int)rays[r * 7 + 6];

  const float z = 0.5f + (3.5f / 127.f) * (float)s;
  const float x = fmaf(dx, z, ox);
  const float y = fmaf(dy, z, oy);
  const float w = fmaf(dz, z, oz);

  const bool keep = (x >= -4.f && x <= 4.f && y >= -4.f && y <= 4.f &&
                     w >= -4.f && w <= 4.f);
  const float xc = fminf(fmaxf(x, -4.f), 4.f);
  const float yc = fminf(fmaxf(y, -4.f), 4.f);
  const float zc = fminf(fmaxf(w, -4.f), 4.f);

  // ---- hash-grid encode: 16 levels x 8 corners ----
  float encp[32];
  #pragma unroll
  for (int l = 0; l < 16; ++l) {
    const float res = RES.r[l];
    const float sc = res * 0.125f;              // res / (BOX_MAX-BOX_MIN)
    const float px = (xc + 4.f) * sc;
    const float py = (yc + 4.f) * sc;
    const float pz = (zc + 4.f) * sc;
    const float bx = floorf(px), by = floorf(py), bz = floorf(pz);
    const float fx = px - bx, fy = py - by, fz = pz - bz;
    const unsigned ix = (unsigned)bx, iy = (unsigned)by, iz = (unsigned)bz;
    const unsigned hx0 = ix, hx1 = ix + 1u;                       // prime 1
    const unsigned hy0 = iy * 2654435761u, hy1 = (iy + 1u) * 2654435761u;
    const unsigned hz0 = iz * 805459861u,  hz1 = (iz + 1u) * 805459861u;
    const float wx0 = 1.f - fx, wy0 = 1.f - fy, wz0 = 1.f - fz;
    const float* tl = tables + (size_t)l * LVL_STRIDE;
    float f0 = 0.f, f1 = 0.f;
    #pragma unroll
    for (int c = 0; c < 8; ++c) {          // OFFSETS order: x outer, z inner
      const unsigned cx = (c >> 2) & 1, cy = (c >> 1) & 1, cz = c & 1;
      const unsigned idx = ((cx ? hx1 : hx0) ^ (cy ? hy1 : hy0) ^ (cz ? hz1 : hz0)) & TBL_MASK;
      const float cw = (cx ? fx : wx0) * (cy ? fy : wy0) * (cz ? fz : wz0);
      const float2 e = *reinterpret_cast<const float2*>(tl + (size_t)idx * 2);
      f0 = fmaf(cw, e.x, f0);
      f1 = fmaf(cw, e.y, f1);
    }
    encp[2 * l] = f0;
    encp[2 * l + 1] = f1;
  }

  // ---- SH degree-4 encode of view dir ----
  float encd[16];
  {
    const float xx = dx * dx, yy = dy * dy, zzv = dz * dz;
    const float xy = dx * dy, yz = dy * dz, xz = dx * dz;
    encd[0]  = 0.28209479177387814f;
    encd[1]  = -0.4886025119029199f * dy;
    encd[2]  = 0.4886025119029199f * dz;
    encd[3]  = -0.4886025119029199f * dx;
    encd[4]  = 1.0925484305920792f * xy;
    encd[5]  = -1.0925484305920792f * yz;
    encd[6]  = 0.31539156525252005f * (2.f * zzv - xx - yy);
    encd[7]  = -1.0925484305920792f * xz;
    encd[8]  = 0.5462742152960396f * (xx - yy);
    encd[9]  = -0.5900435899266435f * dy * (3.f * xx - yy);
    encd[10] = 2.890611442640554f * xy * dz;
    encd[11] = -0.4570457994644658f * dy * (4.f * zzv - xx - yy);
    encd[12] = 0.3731763325901154f * dz * (2.f * zzv - 3.f * xx - 3.f * yy);
    encd[13] = -0.4570457994644658f * dx * (4.f * zzv - xx - yy);
    encd[14] = 1.445305721320277f * dz * (xx - yy);
    encd[15] = -0.5900435899266435f * dx * (xx - 3.f * yy);
  }

  // ---- sigma MLP: 32 -> 64 -> 64 -> 16 ----
  float h1[64]; layer<32, 64>(encp, h1, ws0, true);
  float h2[64]; layer<64, 64>(h1, h2, ws1, true);
  float g[16];  layer<64, 16>(h2, g, ws2, false);

  // ---- color MLP input: [enc_d(16), geo(15), app(16)] ----
  float cin[47];
  #pragma unroll
  for (int i = 0; i < 16; ++i) cin[i] = encd[i];
  #pragma unroll
  for (int i = 0; i < 15; ++i) cin[16 + i] = g[1 + i];
  const float* ap = app_table + code * 16;
  #pragma unroll
  for (int i = 0; i < 16; ++i) cin[31 + i] = ap[i];

  float a1[64]; layer<47, 64>(cin, a1, wc0, true);
  float a2[64]; layer<64, 64>(a1, a2, wc1, true);
  float a3[64]; layer<64, 64>(a2, a3, wc2, true);
  float col[3]; layer<64, 3>(a3, col, wc3, false);

  const float sigma = keep ? g[0] : 0.f;
  float4 o4; o4.x = col[0]; o4.y = col[1]; o4.z = col[2]; o4.w = sigma;
  reinterpret_cast<float4*>(raw_out)[p] = o4;
}

__global__ void __launch_bounds__(256)
render_kernel(const float* __restrict__ rays, const float* __restrict__ raw,
              float* __restrict__ out)
{
  const int r = blockIdx.x * 256 + threadIdx.x;
  if (r >= NRAYS) return;
  const float dx = rays[r * 7 + 3], dy = rays[r * 7 + 4], dz = rays[r * 7 + 5];
  const float nrm = sqrtf(dx * dx + dy * dy + dz * dz);
  const float dstep = 3.5f / 127.f;
  const float4* rp = reinterpret_cast<const float4*>(raw) + (size_t)r * NSAMP;

  // pass 1: compositing
  float T = 1.f, sumw = 0.f, sumwz = 0.f, cm0 = 0.f, cm1 = 0.f, cm2 = 0.f;
  for (int s = 0; s < NSAMP; ++s) {
    const float4 rw = rp[s];
    const float dist = ((s < NSAMP - 1) ? dstep : 1e10f) * nrm;
    const float sig = fmaxf(rw.w, 0.f);
    const float alpha = 1.f - expf(-sig * dist);
    const float wgt = alpha * T;
    T *= (1.f - alpha + 1e-10f);
    const float zv = 0.5f + dstep * (float)s;
    sumw += wgt;
    sumwz = fmaf(wgt, zv, sumwz);
    cm0 = fmaf(wgt, sigmoidf_(rw.x), cm0);
    cm1 = fmaf(wgt, sigmoidf_(rw.y), cm1);
    cm2 = fmaf(wgt, sigmoidf_(rw.z), cm2);
  }

  // pass 2: entropy of normalized weight distribution
  // p = [w_0..w_127, 1-sumw+1e-6], clip >=1e-12, normalize;
  // -sum p log p = log(S1) - S2/S1 with S1=sum q, S2=sum q log q.
  float S1 = 0.f, S2 = 0.f, T2 = 1.f;
  for (int s = 0; s < NSAMP; ++s) {
    const float4 rw = rp[s];
    const float dist = ((s < NSAMP - 1) ? dstep : 1e10f) * nrm;
    const float sig = fmaxf(rw.w, 0.f);
    const float alpha = 1.f - expf(-sig * dist);
    const float wgt = alpha * T2;
    T2 *= (1.f - alpha + 1e-10f);
    const float q = fmaxf(wgt, 1e-12f);
    S1 += q;
    S2 = fmaf(q, logf(q), S2);
  }
  const float plast = fmaxf(1.f - sumw + 1e-6f, 1e-12f);
  S1 += plast;
  S2 = fmaf(plast, logf(plast), S2);
  const float ent = logf(S1) - S2 / S1;

  out[r * 3 + 0] = cm0;
  out[r * 3 + 1] = cm1;
  out[r * 3 + 2] = cm2;
  out[NRAYS * 3 + r] = sumwz;
  out[NRAYS * 4 + r] = ent;
}

extern "C" void kernel_launch(void* const* d_in, const int* in_sizes, int n_in,
                              void* d_out, int out_size, void* d_ws, size_t ws_size,
                              hipStream_t stream)
{
  const float* rays   = (const float*)d_in[0];
  // d_in[1] = app_code (unused by the reference forward)
  const float* tables = (const float*)d_in[2];
  const float* ws0    = (const float*)d_in[3];
  const float* ws1    = (const float*)d_in[4];
  const float* ws2    = (const float*)d_in[5];
  const float* wc0    = (const float*)d_in[6];
  const float* wc1    = (const float*)d_in[7];
  const float* wc2    = (const float*)d_in[8];
  const float* wc3    = (const float*)d_in[9];
  const float* app    = (const float*)d_in[10];

  float* raw = (float*)d_ws;      // 524288 * 4 f32 = 8.4 MB
  float* out = (float*)d_out;

  ResArr RES;
  const double b = exp((log(512.0) - log(16.0)) / 15.0);
  for (int l = 0; l < 16; ++l) RES.r[l] = (float)floor(16.0 * pow(b, (double)l));

  hipLaunchKernelGGL(point_kernel, dim3(NPTS / 256), dim3(256), 0, stream,
                     rays, tables, ws0, ws1, ws2, wc0, wc1, wc2, wc3, app, raw, RES);
  hipLaunchKernelGGL(render_kernel, dim3(NRAYS / 256), dim3(256), 0, stream,
                     rays, raw, out);
}

// Round 4
// 279.379 us; speedup vs baseline: 2.4378x; 2.4378x over previous
//
#include <hip/hip_runtime.h>
#include <math.h>

typedef unsigned short u16;
typedef short bf16x8 __attribute__((ext_vector_type(8)));
typedef float f32x4 __attribute__((ext_vector_type(4)));

#define NRAYS 4096
#define NSAMP 128
#define NPTS (NRAYS * NSAMP)
#define TBL_MASK 0x7FFFFu
#define LVL_STRIDE (524288 * 2)

// d_ws layout (u16 elem offsets for weights): color weights only, then raw
#define WB_C0 0        // [64][64] rows: 0..15 encd, 16..30 geo, 31..46 app, 47..63 zero
#define WB_C1 4096     // [64][64]
#define WB_C2 8192     // [64][64]
#define WB_C3 12288    // [16][64] rows 0..2 = color
#define RAW_OFF 65536  // bf16x4 per point: 4 MB

#define MEMBAR() asm volatile("" ::: "memory")

struct ResArr { float r[16]; };

__device__ __forceinline__ u16 f2b(float f) {   // RNE f32->bf16
  unsigned u = __float_as_uint(f);
  unsigned r = u + 0x7FFFu + ((u >> 16) & 1u);
  return (u16)(r >> 16);
}
__device__ __forceinline__ unsigned pack2(float lo, float hi) {
  return (unsigned)f2b(lo) | ((unsigned)f2b(hi) << 16);
}
__device__ __forceinline__ float b2f(u16 u) {
  return __uint_as_float(((unsigned)u) << 16);
}
__device__ __forceinline__ float sigmoidf_(float x) { return 1.f / (1.f + expf(-x)); }

// round-1-proven scalar f32 layer (sigma path must be f32: sign(sigma) is a
// step function of the output via dist=1e10 -- bf16 noise flips it)
template<int IN, int OUT>
__device__ __forceinline__ void layer(const float (&in)[IN], float (&out)[OUT],
                                      const float* __restrict__ W, bool dorelu)
{
  constexpr int CH = (OUT < 32) ? OUT : 32;
  #pragma unroll
  for (int oc = 0; oc < OUT; oc += CH) {
    float acc[CH];
    #pragma unroll
    for (int o = 0; o < CH; ++o) acc[o] = 0.f;
    #pragma unroll
    for (int i = 0; i < IN; ++i) {
      const float x = in[i];
      const float* wr = W + i * OUT + oc;
      #pragma unroll
      for (int o = 0; o < CH; ++o) acc[o] = fmaf(x, wr[o], acc[o]);
    }
    #pragma unroll
    for (int o = 0; o < CH; ++o) out[oc + o] = dorelu ? fmaxf(acc[o], 0.f) : acc[o];
  }
}

// ---------------- probe MFMA k-pairing + pack color weights ----------------
// Probe: A slot (g*8+e) holds value g*8+e+1 (same in all lanes); B is one-hot
// at slot t. D[i][j] is then constant = (A-slot paired with B-slot t)+1,
// independent of any layout assumption. Weights get packed with P^-1 so the
// kernel is correct for ANY (even asymmetric) A/B k-map.
__global__ void __launch_bounds__(256)
prep_kernel(const float* __restrict__ wc0, const float* __restrict__ wc1,
            const float* __restrict__ wc2, const float* __restrict__ wc3,
            u16* __restrict__ wb)
{
  __shared__ int P[32];
  __shared__ int Pinv[32];
  const int t = threadIdx.x;
  if (t < 64) {
    const int g = t >> 4;
    for (int tt = 0; tt < 32; ++tt) {
      bf16x8 A, B;
      #pragma unroll
      for (int e = 0; e < 8; ++e) {
        A[e] = (short)f2b((float)(g * 8 + e + 1));
        B[e] = (short)((g * 8 + e == tt) ? 0x3F80 : 0);   // bf16(1.0)
      }
      f32x4 c = {0.f, 0.f, 0.f, 0.f};
      c = __builtin_amdgcn_mfma_f32_16x16x32_bf16(A, B, c, 0, 0, 0);
      if (t == 0) P[tt] = (int)(c[0] + 0.5f) - 1;
    }
  }
  __syncthreads();
  if (t < 32) Pinv[t] = t;
  __syncthreads();
  if (t < 32) { int p = P[t]; if (p >= 0 && p < 32) Pinv[p] = t; }
  __syncthreads();

  // pack [out][in] bf16, permuting k within each 32-wide chunk by Pinv
  for (int i = t; i < 4096; i += 256) {
    int o = i >> 6, s6 = i & 63, kt = (s6 & 32) | Pinv[s6 & 31];
    wb[WB_C0 + i] = f2b(kt < 47 ? wc0[kt * 64 + o] : 0.f);
  }
  for (int i = t; i < 4096; i += 256) {
    int o = i >> 6, s6 = i & 63, kt = (s6 & 32) | Pinv[s6 & 31];
    wb[WB_C1 + i] = f2b(wc1[kt * 64 + o]);
  }
  for (int i = t; i < 4096; i += 256) {
    int o = i >> 6, s6 = i & 63, kt = (s6 & 32) | Pinv[s6 & 31];
    wb[WB_C2 + i] = f2b(wc2[kt * 64 + o]);
  }
  for (int i = t; i < 1024; i += 256) {
    int o = i >> 6, s6 = i & 63, kt = (s6 & 32) | Pinv[s6 & 31];
    wb[WB_C3 + i] = f2b(o < 3 ? wc3[kt * 3 + o] : 0.f);
  }
}

// ---------------- fused encode + f32 sigma MLP + bf16 MFMA color MLP ----------------
__global__ void __launch_bounds__(256, 4)
point_kernel(const float* __restrict__ rays, const float* __restrict__ tables,
             const float* __restrict__ ws0, const float* __restrict__ ws1,
             const float* __restrict__ ws2, const u16* __restrict__ wb,
             const float* __restrict__ app_table, u16* __restrict__ raw, ResArr RES)
{
  __shared__ char lds[4 * 8192 + 4 * 64 * 4];
  const int t = threadIdx.x, wv = t >> 6, lane = t & 63;
  char* buf = lds + wv * 8192;
  float* sigb = (float*)(lds + 32768 + wv * 256);
  const int pBase = blockIdx.x * 256 + wv * 64;
  const int q = lane & 15, g = lane >> 4;
  const unsigned fswz = (unsigned)((q & 7) << 4);
  const unsigned myswz = (unsigned)((lane & 7) << 4);

  // ---------- phase 1: per-thread encode + scalar f32 sigma MLP ----------
  const int ptG = pBase + lane;
  const int r = ptG >> 7, s = ptG & (NSAMP - 1);
  const float ox = rays[r * 7 + 0], oy = rays[r * 7 + 1], oz = rays[r * 7 + 2];
  const float dx = rays[r * 7 + 3], dy = rays[r * 7 + 4], dz = rays[r * 7 + 5];
  const int code = (int)rays[r * 7 + 6];
  const float z = 0.5f + (3.5f / 127.f) * (float)s;
  const float x = fmaf(dx, z, ox), y = fmaf(dy, z, oy), w = fmaf(dz, z, oz);
  const bool keep = (x >= -4.f && x <= 4.f && y >= -4.f && y <= 4.f &&
                     w >= -4.f && w <= 4.f);
  const float xc = fminf(fmaxf(x, -4.f), 4.f);
  const float yc = fminf(fmaxf(y, -4.f), 4.f);
  const float zc = fminf(fmaxf(w, -4.f), 4.f);

  float encp[32];
  #pragma unroll
  for (int l = 0; l < 16; ++l) {
    const float res = RES.r[l];
    const float sc = res * 0.125f;
    const float px = (xc + 4.f) * sc, py = (yc + 4.f) * sc, pz = (zc + 4.f) * sc;
    const float bx = floorf(px), by = floorf(py), bz = floorf(pz);
    const float fx = px - bx, fy = py - by, fz = pz - bz;
    const unsigned ix = (unsigned)bx, iy = (unsigned)by, iz = (unsigned)bz;
    const unsigned hx0 = ix, hx1 = ix + 1u;
    const unsigned hy0 = iy * 2654435761u, hy1 = (iy + 1u) * 2654435761u;
    const unsigned hz0 = iz * 805459861u,  hz1 = (iz + 1u) * 805459861u;
    const float wx0 = 1.f - fx, wy0 = 1.f - fy, wz0 = 1.f - fz;
    const float* tl = tables + (size_t)l * LVL_STRIDE;
    float f0 = 0.f, f1 = 0.f;
    #pragma unroll
    for (int c = 0; c < 8; ++c) {
      const unsigned cx = (c >> 2) & 1, cy = (c >> 1) & 1, cz = c & 1;
      const unsigned idx = ((cx ? hx1 : hx0) ^ (cy ? hy1 : hy0) ^ (cz ? hz1 : hz0)) & TBL_MASK;
      const float cw = (cx ? fx : wx0) * (cy ? fy : wy0) * (cz ? fz : wz0);
      const float2 e = *reinterpret_cast<const float2*>(tl + (size_t)idx * 2);
      f0 = fmaf(cw, e.x, f0);
      f1 = fmaf(cw, e.y, f1);
    }
    encp[2 * l] = f0;
    encp[2 * l + 1] = f1;
  }

  // sigma MLP fully in f32 (round-1-proven)
  float h1[64]; layer<32, 64>(encp, h1, ws0, true);
  float h2[64]; layer<64, 64>(h1, h2, ws1, true);
  float gg[16]; layer<64, 16>(h2, gg, ws2, false);
  sigb[lane] = keep ? gg[0] : 0.f;

  // color input row: slots 0..15 encd, 16..30 geo, 31..46 app, 47..63 zero
  {
    float cin[64];
    const float xx = dx * dx, yy = dy * dy, zz2 = dz * dz;
    const float xy = dx * dy, yz = dy * dz, xz = dx * dz;
    cin[0]  = 0.28209479177387814f;
    cin[1]  = -0.4886025119029199f * dy;
    cin[2]  = 0.4886025119029199f * dz;
    cin[3]  = -0.4886025119029199f * dx;
    cin[4]  = 1.0925484305920792f * xy;
    cin[5]  = -1.0925484305920792f * yz;
    cin[6]  = 0.31539156525252005f * (2.f * zz2 - xx - yy);
    cin[7]  = -1.0925484305920792f * xz;
    cin[8]  = 0.5462742152960396f * (xx - yy);
    cin[9]  = -0.5900435899266435f * dy * (3.f * xx - yy);
    cin[10] = 2.890611442640554f * xy * dz;
    cin[11] = -0.4570457994644658f * dy * (4.f * zz2 - xx - yy);
    cin[12] = 0.3731763325901154f * dz * (2.f * zz2 - 3.f * xx - 3.f * yy);
    cin[13] = -0.4570457994644658f * dx * (4.f * zz2 - xx - yy);
    cin[14] = 1.445305721320277f * dz * (xx - yy);
    cin[15] = -0.5900435899266435f * dx * (xx - 3.f * yy);
    #pragma unroll
    for (int i = 0; i < 15; ++i) cin[16 + i] = gg[1 + i];
    const float4* ap = (const float4*)(app_table + (size_t)code * 16);
    float4 a0 = ap[0], a1 = ap[1], a2 = ap[2], a3 = ap[3];
    cin[31] = a0.x; cin[32] = a0.y; cin[33] = a0.z; cin[34] = a0.w;
    cin[35] = a1.x; cin[36] = a1.y; cin[37] = a1.z; cin[38] = a1.w;
    cin[39] = a2.x; cin[40] = a2.y; cin[41] = a2.z; cin[42] = a2.w;
    cin[43] = a3.x; cin[44] = a3.y; cin[45] = a3.z; cin[46] = a3.w;
    #pragma unroll
    for (int i = 47; i < 64; ++i) cin[i] = 0.f;
    #pragma unroll
    for (int c = 0; c < 8; ++c) {
      uint4 u;
      u.x = pack2(cin[8 * c + 0], cin[8 * c + 1]);
      u.y = pack2(cin[8 * c + 2], cin[8 * c + 3]);
      u.z = pack2(cin[8 * c + 4], cin[8 * c + 5]);
      u.w = pack2(cin[8 * c + 6], cin[8 * c + 7]);
      *(uint4*)(buf + lane * 128 + (((unsigned)(c * 16)) ^ myswz)) = u;
    }
  }
  MEMBAR();   // pack stores -> c0 loads

  // ---------- phase 2: color MFMA MLP (wave-private, no barriers) ----------
  auto rdB = [&](int n, int kc) -> bf16x8 {
    return *(const bf16x8*)(buf + (n * 16 + q) * 128 + (((unsigned)(kc * 64 + g * 16)) ^ fswz));
  };
  auto ldA = [&](const u16* Wp, int row, int kc) -> bf16x8 {
    return *(const bf16x8*)(Wp + row * 64 + kc * 32 + g * 8);
  };
  auto wrC = [&](int n, int slot0, f32x4 c) {
    c[0] = fmaxf(c[0], 0.f); c[1] = fmaxf(c[1], 0.f);
    c[2] = fmaxf(c[2], 0.f); c[3] = fmaxf(c[3], 0.f);
    uint2 u; u.x = pack2(c[0], c[1]); u.y = pack2(c[2], c[3]);
    *(uint2*)(buf + (n * 16 + q) * 128 + (((unsigned)(slot0 * 2)) ^ fswz)) = u;
  };

  auto layer64 = [&](const u16* Wp) {   // 64 -> 64 + relu
    bf16x8 A[4][2];
    #pragma unroll
    for (int m = 0; m < 4; ++m) {
      A[m][0] = ldA(Wp, m * 16 + q, 0);
      A[m][1] = ldA(Wp, m * 16 + q, 1);
    }
    #pragma unroll
    for (int n = 0; n < 4; ++n) {
      bf16x8 b0 = rdB(n, 0), b1 = rdB(n, 1);
      #pragma unroll
      for (int m = 0; m < 4; ++m) {
        f32x4 c = f32x4{0.f, 0.f, 0.f, 0.f};
        c = __builtin_amdgcn_mfma_f32_16x16x32_bf16(A[m][0], b0, c, 0, 0, 0);
        c = __builtin_amdgcn_mfma_f32_16x16x32_bf16(A[m][1], b1, c, 0, 0, 0);
        wrC(n, m * 16 + g * 4, c);
      }
    }
    MEMBAR();
  };

  layer64(wb + WB_C0);  // c0
  layer64(wb + WB_C1);  // c1
  layer64(wb + WB_C2);  // c2

  // c3: 64 -> 3 colors (+ f32-path sigma) -> global raw (bf16x4 per point)
  {
    const u16* Wp = wb + WB_C3;
    bf16x8 A0 = ldA(Wp, q, 0), A1 = ldA(Wp, q, 1);
    #pragma unroll
    for (int n = 0; n < 4; ++n) {
      bf16x8 b0 = rdB(n, 0), b1 = rdB(n, 1);
      f32x4 c = f32x4{0.f, 0.f, 0.f, 0.f};
      c = __builtin_amdgcn_mfma_f32_16x16x32_bf16(A0, b0, c, 0, 0, 0);
      c = __builtin_amdgcn_mfma_f32_16x16x32_bf16(A1, b1, c, 0, 0, 0);
      if (g == 0) {
        uint2 o; o.x = pack2(c[0], c[1]); o.y = pack2(c[2], sigb[n * 16 + q]);
        *(uint2*)(raw + (size_t)(pBase + n * 16 + q) * 4) = o;
      }
    }
  }
}

// ---------------- per-ray compositing ----------------
__global__ void __launch_bounds__(256)
render_kernel(const float* __restrict__ rays, const u16* __restrict__ raw,
              float* __restrict__ out)
{
  const int r = blockIdx.x * 256 + threadIdx.x;
  if (r >= NRAYS) return;
  const float dx = rays[r * 7 + 3], dy = rays[r * 7 + 4], dz = rays[r * 7 + 5];
  const float nrm = sqrtf(dx * dx + dy * dy + dz * dz);
  const float dstep = 3.5f / 127.f;
  const ushort4* rp = reinterpret_cast<const ushort4*>(raw) + (size_t)r * NSAMP;

  float T = 1.f, sumw = 0.f, sumwz = 0.f, cm0 = 0.f, cm1 = 0.f, cm2 = 0.f;
  for (int s = 0; s < NSAMP; ++s) {
    const ushort4 rw = rp[s];
    const float dist = ((s < NSAMP - 1) ? dstep : 1e10f) * nrm;
    const float sigv = fmaxf(b2f(rw.w), 0.f);
    const float alpha = 1.f - expf(-sigv * dist);
    const float wgt = alpha * T;
    T *= (1.f - alpha + 1e-10f);
    const float zv = 0.5f + dstep * (float)s;
    sumw += wgt;
    sumwz = fmaf(wgt, zv, sumwz);
    cm0 = fmaf(wgt, sigmoidf_(b2f(rw.x)), cm0);
    cm1 = fmaf(wgt, sigmoidf_(b2f(rw.y)), cm1);
    cm2 = fmaf(wgt, sigmoidf_(b2f(rw.z)), cm2);
  }

  float S1 = 0.f, S2 = 0.f, T2 = 1.f;
  for (int s = 0; s < NSAMP; ++s) {
    const ushort4 rw = rp[s];
    const float dist = ((s < NSAMP - 1) ? dstep : 1e10f) * nrm;
    const float sigv = fmaxf(b2f(rw.w), 0.f);
    const float alpha = 1.f - expf(-sigv * dist);
    const float wgt = alpha * T2;
    T2 *= (1.f - alpha + 1e-10f);
    const float qv = fmaxf(wgt, 1e-12f);
    S1 += qv;
    S2 = fmaf(qv, logf(qv), S2);
  }
  const float plast = fmaxf(1.f - sumw + 1e-6f, 1e-12f);
  S1 += plast;
  S2 = fmaf(plast, logf(plast), S2);
  const float ent = logf(S1) - S2 / S1;

  out[r * 3 + 0] = cm0;
  out[r * 3 + 1] = cm1;
  out[r * 3 + 2] = cm2;
  out[NRAYS * 3 + r] = sumwz;
  out[NRAYS * 4 + r] = ent;
}

extern "C" void kernel_launch(void* const* d_in, const int* in_sizes, int n_in,
                              void* d_out, int out_size, void* d_ws, size_t ws_size,
                              hipStream_t stream)
{
  const float* rays   = (const float*)d_in[0];
  const float* tables = (const float*)d_in[2];
  const float* ws0    = (const float*)d_in[3];
  const float* ws1    = (const float*)d_in[4];
  const float* ws2    = (const float*)d_in[5];
  const float* wc0    = (const float*)d_in[6];
  const float* wc1    = (const float*)d_in[7];
  const float* wc2    = (const float*)d_in[8];
  const float* wc3    = (const float*)d_in[9];
  const float* app    = (const float*)d_in[10];

  u16* wb  = (u16*)d_ws;
  u16* raw = (u16*)((char*)d_ws + RAW_OFF);
  float* out = (float*)d_out;

  ResArr RES;
  const double b = exp((log(512.0) - log(16.0)) / 15.0);
  for (int l = 0; l < 16; ++l) RES.r[l] = (float)floor(16.0 * pow(b, (double)l));

  hipLaunchKernelGGL(prep_kernel, dim3(1), dim3(256), 0, stream,
                     wc0, wc1, wc2, wc3, wb);
  hipLaunchKernelGGL(point_kernel, dim3(NPTS / 256), dim3(256), 0, stream,
                     rays, tables, ws0, ws1, ws2, wb, app, raw, RES);
  hipLaunchKernelGGL(render_kernel, dim3(16), dim3(256), 0, stream,
                     rays, raw, out);
}